// Round 11
// baseline (758.865 us; speedup 1.0000x reference)
//
#include <hip/hip_runtime.h>

// AutoregressiveForecaster R11: R10 (2 tiles/block, in-wave ILP) with the
// window-init OOB bug fixed. 2-layer LSTM(H=64) + MLP head, 20 steps, B=8192.
//
//  - 256 blocks x 256 threads (4 waves). Block owns TWO independent 16-batch
//    tiles (A=blk*32, B=blk*32+16). Each wave processes its gate-quad for BOTH
//    tiles in one instruction stream -> 2 independent dependency chains per
//    wave fill each other's MFMA/trans/DS latency (R9's ~47% bubble).
//  - Weight B-frags in VGPRs are SHARED across tiles (96 regs reused).
//  - 1 block/CU, 1 wave/SIMD, ~250 VGPR (launch_bounds(256,1); arg2 =
//    min blocks/CU per R6/R7 evidence).
//  - Wave w owns gate-tiles {w,w+4,w+8,w+12} = gates i,f,g,o of units
//    [16w,16w+16): elementwise lane-local, c-state in registers.
//  - Pipelined: iter t computes L1(t) [K=128] + L0(t+1) [K=64] for both tiles,
//    ping-pong staging, 1 __syncthreads/iter.
//  - Fused-7 gates (R8/R9-verified): 5 exp2 + 2 rcp per unit-step.
//  - MLP head: waves 0,1 -> tile A halves; waves 2,3 -> tile B halves.
//  - R10 bug: window init used q=e>>8 / rem=e&255 for 384-elem tiles ->
//    t=16..23 uninitialized + win[2] OOB write + x OOB read. Fixed with
//    explicit q = (e>=384), rem = e - 384q.

typedef _Float16 f16x8 __attribute__((ext_vector_type(8)));
typedef float f32x4 __attribute__((ext_vector_type(4)));

#define NBLK 256
#define NTHR 256
#define SRB  144   // h row stride bytes

__device__ __forceinline__ float rcp_(float x) { return __builtin_amdgcn_rcpf(x); }
__device__ __forceinline__ float exp2_(float x) { return __builtin_amdgcn_exp2f(x); }
__device__ __forceinline__ f32x4 mfma16(uint4 a, uint4 b, f32x4 c) {
  return __builtin_amdgcn_mfma_f32_16x16x32_f16(
      __builtin_bit_cast(f16x8, a), __builtin_bit_cast(f16x8, b), c, 0, 0, 0);
}
__device__ __forceinline__ uint4 pack8s(const float* p, float s) {
  union { uint4 u; _Float16 h[8]; } r;
  #pragma unroll
  for (int i = 0; i < 8; ++i) r.h[i] = (_Float16)(p[i] * s);
  return r.u;
}
// fused LSTM gate update; pre-activations pre-scaled by log2e (2x for g-gate).
__device__ __forceinline__ float gatestep(float aI, float aF, float aG, float aO,
                                          float& cst) {
  float xx = exp2_(-aI), xf = exp2_(-aF), yy = exp2_(-aG), xo = exp2_(-aO);
  float P = (1.0f + xx) * (1.0f + yy);
  float Q = 1.0f + xf;
  float N = fmaf(cst, P, (1.0f - yy) * Q);   // c*P + (1-yy)*Q
  float cv = N * rcp_(P * Q);
  cst = cv;
  float z = exp2_(-2.88539008178f * cv);
  return (1.0f - z) * rcp_((1.0f + xo) * (1.0f + z));
}

__global__ __launch_bounds__(NTHR, 1) void lstm_forecast(
    const float* __restrict__ x,
    const float* __restrict__ Wih0, const float* __restrict__ Whh0,
    const float* __restrict__ bih0, const float* __restrict__ bhh0,
    const float* __restrict__ Wih1, const float* __restrict__ Whh1,
    const float* __restrict__ bih1, const float* __restrict__ bhh1,
    const float* __restrict__ W1,   const float* __restrict__ b1,
    const float* __restrict__ W2,   const float* __restrict__ b2,
    const float* __restrict__ damping, const int* __restrict__ stepsPtr,
    float* __restrict__ out)
{
  __shared__ __align__(16) char h1s[2][2][16 * SRB];   // [tile][parity]
  __shared__ __align__(16) char h2s[2][2][16 * SRB];
  __shared__ __align__(16) float win[2][24 * 16];
  __shared__ __align__(16) float pm[2][2][16];         // [tile][half]

  const int tid  = threadIdx.x;
  const int wave = tid >> 6;
  const int lane = tid & 63;
  const int cc   = lane & 15;
  const int hi   = lane >> 4;
  const int b0g  = blockIdx.x * 32;                    // tile A base; B = +16
  const float L2E = 1.44269504089f;

  // ---- weight B-fragments into VGPRs (shared across both tiles) ----
  uint4 wB0[4][2], wB1[4][2], wB2[4][2];
  float bias0v[4], wih0v[4];
  f32x4 bi1[4];
  #pragma unroll
  for (int gt = 0; gt < 4; ++gt) {
    float sc = (gt == 2) ? 2.0f * L2E : L2E;
    int row = (wave + 4 * gt) * 16 + cc;
    #pragma unroll
    for (int f = 0; f < 2; ++f) {
      int col = f * 32 + hi * 8;
      wB0[gt][f] = pack8s(Whh0 + row * 64 + col, sc);
      wB1[gt][f] = pack8s(Wih1 + row * 64 + col, sc);
      wB2[gt][f] = pack8s(Whh1 + row * 64 + col, sc);
    }
    bias0v[gt] = (bih0[row] + bhh0[row]) * sc;
    wih0v[gt]  = Wih0[row] * sc;
    float b1c  = (bih1[row] + bhh1[row]) * sc;
    #pragma unroll
    for (int r = 0; r < 4; ++r) bi1[gt][r] = b1c;
  }
  // MLP fragments: neuron-half = wave&1; tile chosen at use (wave>>1)
  uint4 wM[2];
  {
    int row = (wave & 1) * 16 + cc;
    wM[0] = pack8s(W1 + row * 64 + hi * 8, 1.0f);
    wM[1] = pack8s(W1 + row * 64 + 32 + hi * 8, 1.0f);
  }
  const float w2v  = W2[(wave & 1) * 16 + cc];
  const float b1vv = b1[(wave & 1) * 16 + cc];
  const float alpha  = rcp_(1.0f + exp2_(-L2E * damping[0]));
  const int   nsteps = stepsPtr[0];
  const float b2v    = b2[0];

  // window init (FIXED): 2 tiles x 384 elems; win[q][t*16+b] = x[(b0g+16q+b)*24+t]
  for (int e = tid; e < 768; e += NTHR) {
    int q   = (e >= 384) ? 1 : 0;
    int rem = e - q * 384;
    int b   = rem & 15, t = rem >> 4;
    win[q][t * 16 + b] = x[(b0g + q * 16 + b) * 24 + t];
  }
  __syncthreads();

  const int offA = cc * SRB + hi * 16;
  const int offS = (wave * 16 + cc) * 2;
  float prevp[2] = {0.0f, 0.0f};

  for (int s = 0; s < nsteps; ++s) {
    float c1[2][4], c2s[2][4];
    #pragma unroll
    for (int q = 0; q < 2; ++q)
      #pragma unroll
      for (int r = 0; r < 4; ++r) { c1[q][r] = 0.0f; c2s[q][r] = 0.0f; }

    // ---- prologue: L0(0) elementwise (h1(-1)=0), both tiles ----
    #pragma unroll
    for (int q = 0; q < 2; ++q) {
      float4 xw = *(const float4*)&win[q][(s % 24) * 16 + hi * 4];
      float xa[4] = {xw.x, xw.y, xw.z, xw.w};
      #pragma unroll
      for (int r = 0; r < 4; ++r) {
        float hv = gatestep(fmaf(xa[r], wih0v[0], bias0v[0]),
                            fmaf(xa[r], wih0v[1], bias0v[1]),
                            fmaf(xa[r], wih0v[2], bias0v[2]),
                            fmaf(xa[r], wih0v[3], bias0v[3]), c1[q][r]);
        *(_Float16*)(h1s[q][0] + (hi * 4 + r) * SRB + offS) = (_Float16)hv;
      }
    }
    __syncthreads();
    uint4 a1lo[2], a1hi[2], a2lo[2], a2hi[2];
    #pragma unroll
    for (int q = 0; q < 2; ++q) {
      a1lo[q] = *(const uint4*)(h1s[q][0] + offA);
      a1hi[q] = *(const uint4*)(h1s[q][0] + offA + 64);
      a2lo[q] = make_uint4(0, 0, 0, 0);
      a2hi[q] = make_uint4(0, 0, 0, 0);
    }

    // ---- main pipelined loop: iter t = L1(t) + L0(t+1), both tiles ----
    for (int t = 0; t < 23; ++t) {
      int pb = (t + 1) & 1;
      int ph = s + t + 1; if (ph >= 24) ph -= 24;

      f32x4 acc1[2][4], acc0[2][4];
      // all 48 MFMAs first: two independent chains per gt fill the pipe
      #pragma unroll
      for (int q = 0; q < 2; ++q) {
        #pragma unroll
        for (int gt = 0; gt < 4; ++gt) {
          f32x4 tv = mfma16(a1lo[q], wB1[gt][0], bi1[gt]);
          tv = mfma16(a1hi[q], wB1[gt][1], tv);
          tv = mfma16(a2lo[q], wB2[gt][0], tv);
          acc1[q][gt] = mfma16(a2hi[q], wB2[gt][1], tv);
        }
      }
      #pragma unroll
      for (int q = 0; q < 2; ++q) {
        float4 xw = *(const float4*)&win[q][ph * 16 + hi * 4];
        float xa[4] = {xw.x, xw.y, xw.z, xw.w};
        #pragma unroll
        for (int gt = 0; gt < 4; ++gt) {
          f32x4 ai;
          #pragma unroll
          for (int r = 0; r < 4; ++r) ai[r] = fmaf(xa[r], wih0v[gt], bias0v[gt]);
          f32x4 tv = mfma16(a1lo[q], wB0[gt][0], ai);
          acc0[q][gt] = mfma16(a1hi[q], wB0[gt][1], tv);
        }
      }

      // gatesteps: two tiles back-to-back give the trans pipe ILP
      #pragma unroll
      for (int q = 0; q < 2; ++q) {
        char* h2d = h2s[q][pb];
        char* h1d = h1s[q][pb];
        #pragma unroll
        for (int r = 0; r < 4; ++r) {
          float hv = gatestep(acc1[q][0][r], acc1[q][1][r], acc1[q][2][r],
                              acc1[q][3][r], c2s[q][r]);
          *(_Float16*)(h2d + (hi * 4 + r) * SRB + offS) = (_Float16)hv;
        }
        #pragma unroll
        for (int r = 0; r < 4; ++r) {
          float hv = gatestep(acc0[q][0][r], acc0[q][1][r], acc0[q][2][r],
                              acc0[q][3][r], c1[q][r]);
          *(_Float16*)(h1d + (hi * 4 + r) * SRB + offS) = (_Float16)hv;
        }
      }
      __syncthreads();
      #pragma unroll
      for (int q = 0; q < 2; ++q) {
        a1lo[q] = *(const uint4*)(h1s[q][pb] + offA);
        a1hi[q] = *(const uint4*)(h1s[q][pb] + offA + 64);
        a2lo[q] = *(const uint4*)(h2s[q][pb] + offA);
        a2hi[q] = *(const uint4*)(h2s[q][pb] + offA + 64);
      }
    } // t

    // ---- epilogue: L1(23) both tiles -> h2s[q][0] ----
    #pragma unroll
    for (int q = 0; q < 2; ++q) {
      f32x4 acc1[4];
      #pragma unroll
      for (int gt = 0; gt < 4; ++gt) {
        f32x4 tv = mfma16(a1lo[q], wB1[gt][0], bi1[gt]);
        tv = mfma16(a1hi[q], wB1[gt][1], tv);
        tv = mfma16(a2lo[q], wB2[gt][0], tv);
        acc1[gt] = mfma16(a2hi[q], wB2[gt][1], tv);
      }
      #pragma unroll
      for (int r = 0; r < 4; ++r) {
        float cv = c2s[q][r];
        float hv = gatestep(acc1[0][r], acc1[1][r], acc1[2][r], acc1[3][r], cv);
        *(_Float16*)(h2s[q][0] + (hi * 4 + r) * SRB + offS) = (_Float16)hv;
      }
    }
    __syncthreads();

    // ---- MLP head: waves 0,1 -> tile 0; waves 2,3 -> tile 1 ----
    {
      const int tq = wave >> 1;
      uint4 hflo = *(const uint4*)(h2s[tq][0] + offA);
      uint4 hfhi = *(const uint4*)(h2s[tq][0] + offA + 64);
      f32x4 am;
      #pragma unroll
      for (int r = 0; r < 4; ++r) am[r] = b1vv;
      am = mfma16(hflo, wM[0], am);
      am = mfma16(hfhi, wM[1], am);
      float yp[4];
      #pragma unroll
      for (int r = 0; r < 4; ++r) yp[r] = fmaxf(am[r], 0.0f) * w2v;
      #pragma unroll
      for (int mask = 1; mask <= 8; mask <<= 1) {
        #pragma unroll
        for (int r = 0; r < 4; ++r) yp[r] += __shfl_xor(yp[r], mask);
      }
      if (cc == 0) {
        #pragma unroll
        for (int r = 0; r < 4; ++r) pm[tq][wave & 1][hi * 4 + r] = yp[r];
      }
    }
    __syncthreads();

    // all waves compute both tiles' pd (uniform); waves 0/2 lane<16 write
    #pragma unroll
    for (int q = 0; q < 2; ++q) {
      if (lane < 16) {
        float y = pm[q][0][lane] + pm[q][1][lane] + b2v;
        float pd = (s == 0) ? y
                            : fmaf(y, 1.0f - alpha, prevp[q] * (alpha * 0.5f));
        prevp[q] = pd;
        if (wave == 2 * q) {
          win[q][(s % 24) * 16 + lane] = pd;
          out[(long)(b0g + q * 16 + lane) * nsteps + s] = pd;
        }
      }
    }
    __syncthreads();
  } // s
}

extern "C" void kernel_launch(void* const* d_in, const int* in_sizes, int n_in,
                              void* d_out, int out_size, void* d_ws, size_t ws_size,
                              hipStream_t stream) {
  (void)in_sizes; (void)n_in; (void)out_size; (void)d_ws; (void)ws_size;
  lstm_forecast<<<NBLK, NTHR, 0, stream>>>(
      (const float*)d_in[0],
      (const float*)d_in[1],  (const float*)d_in[2],
      (const float*)d_in[3],  (const float*)d_in[4],
      (const float*)d_in[5],  (const float*)d_in[6],
      (const float*)d_in[7],  (const float*)d_in[8],
      (const float*)d_in[9],  (const float*)d_in[10],
      (const float*)d_in[11], (const float*)d_in[12],
      (const float*)d_in[13], (const int*)d_in[14],
      (float*)d_out);
}

// Round 12
// 628.690 us; speedup vs baseline: 1.2071x; 1.2071x over previous
//
#include <hip/hip_runtime.h>

// AutoregressiveForecaster R12: R9 base + cross-step interval folding.
// 2-layer LSTM(H=64) + MLP head, 20 autoregressive steps, 24-window, B=8192.
//
//  - 512 blocks x 256 threads (4 waves), block owns one 16-batch MFMA M-tile,
//    2 blocks/CU (launch_bounds(256,2); arg2 = min blocks/CU per R6/R7).
//  - Wave w owns gate-tiles {w,w+4,w+8,w+12} = gates i,f,g,o of units
//    [16w,16w+16): elementwise lane-local, c-state in registers.
//  - INTERVAL FOLDING (28 -> 24 barriers/step): pred(s-1) is only read at
//    iter t=22 of step s, so:
//      iter23 = L1(23) + L0(0)-of-next-step (elementwise, new c1 chain)
//      MLP(s-1) rides in iter0 of step s (h2(23) frags read at the seam)
//      blend+win/out write rides at top of iter1 of step s
//  - Fused-7 gates (R8/R9-verified): 5 exp2 + 2 rcp per unit-step.
//  - Weights pre-scaled by log2e (2x g-gate), LSTM B-frags in VGPRs (24 uint4);
//    MLP W1 frags in LDS (read once per step) to offset hflo/hfhi liveness.

typedef _Float16 f16x8 __attribute__((ext_vector_type(8)));
typedef float f32x4 __attribute__((ext_vector_type(4)));

#define NBLK 512
#define NTHR 256
#define SRB  144   // h row stride bytes

__device__ __forceinline__ float rcp_(float x) { return __builtin_amdgcn_rcpf(x); }
__device__ __forceinline__ float exp2_(float x) { return __builtin_amdgcn_exp2f(x); }
__device__ __forceinline__ f32x4 mfma16(uint4 a, uint4 b, f32x4 c) {
  return __builtin_amdgcn_mfma_f32_16x16x32_f16(
      __builtin_bit_cast(f16x8, a), __builtin_bit_cast(f16x8, b), c, 0, 0, 0);
}
__device__ __forceinline__ uint4 pack8s(const float* p, float s) {
  union { uint4 u; _Float16 h[8]; } r;
  #pragma unroll
  for (int i = 0; i < 8; ++i) r.h[i] = (_Float16)(p[i] * s);
  return r.u;
}
// fused LSTM gate update; pre-activations pre-scaled by log2e (2x for g-gate).
__device__ __forceinline__ float gatestep(float aI, float aF, float aG, float aO,
                                          float& cst) {
  float xx = exp2_(-aI), xf = exp2_(-aF), yy = exp2_(-aG), xo = exp2_(-aO);
  float P = (1.0f + xx) * (1.0f + yy);
  float Q = 1.0f + xf;
  float N = fmaf(cst, P, (1.0f - yy) * Q);   // c*P + (1-yy)*Q
  float cv = N * rcp_(P * Q);
  cst = cv;
  float z = exp2_(-2.88539008178f * cv);
  return (1.0f - z) * rcp_((1.0f + xo) * (1.0f + z));
}

__global__ __launch_bounds__(NTHR, 2) void lstm_forecast(
    const float* __restrict__ x,
    const float* __restrict__ Wih0, const float* __restrict__ Whh0,
    const float* __restrict__ bih0, const float* __restrict__ bhh0,
    const float* __restrict__ Wih1, const float* __restrict__ Whh1,
    const float* __restrict__ bih1, const float* __restrict__ bhh1,
    const float* __restrict__ W1,   const float* __restrict__ b1,
    const float* __restrict__ W2,   const float* __restrict__ b2,
    const float* __restrict__ damping, const int* __restrict__ stepsPtr,
    float* __restrict__ out)
{
  __shared__ __align__(16) char h1s[2][16 * SRB];
  __shared__ __align__(16) char h2s[2][16 * SRB];
  __shared__ __align__(16) float win[24 * 16];
  __shared__ __align__(16) float pm[2][16];
  __shared__ __align__(16) uint4 wfm[4][64];   // MLP W1 frags [half*2+f][lane]

  const int tid  = threadIdx.x;
  const int wave = tid >> 6;
  const int lane = tid & 63;
  const int cc   = lane & 15;
  const int hi   = lane >> 4;
  const int b0g  = blockIdx.x * 16;
  const float L2E = 1.44269504089f;

  // ---- LSTM weight B-fragments into VGPRs (pre-scaled) ----
  uint4 wB0[4][2], wB1[4][2], wB2[4][2];
  float bias0v[4], wih0v[4];
  f32x4 bi1[4];
  #pragma unroll
  for (int gt = 0; gt < 4; ++gt) {
    float sc = (gt == 2) ? 2.0f * L2E : L2E;
    int row = (wave + 4 * gt) * 16 + cc;
    #pragma unroll
    for (int f = 0; f < 2; ++f) {
      int col = f * 32 + hi * 8;
      wB0[gt][f] = pack8s(Whh0 + row * 64 + col, sc);
      wB1[gt][f] = pack8s(Wih1 + row * 64 + col, sc);
      wB2[gt][f] = pack8s(Whh1 + row * 64 + col, sc);
    }
    bias0v[gt] = (bih0[row] + bhh0[row]) * sc;
    wih0v[gt]  = Wih0[row] * sc;
    float b1c  = (bih1[row] + bhh1[row]) * sc;
    #pragma unroll
    for (int r = 0; r < 4; ++r) bi1[gt][r] = b1c;
  }
  // MLP W1 frags -> LDS (cold: read once per step)
  for (int e = tid; e < 256; e += NTHR) {
    int l = e & 63, f = (e >> 6) & 1, n = e >> 7;
    wfm[n * 2 + f][l] =
        pack8s(W1 + (n * 16 + (l & 15)) * 64 + f * 32 + (l >> 4) * 8, 1.0f);
  }
  const float w2v  = W2[(wave & 1) * 16 + cc];
  const float b1vv = b1[(wave & 1) * 16 + cc];
  const float alpha  = rcp_(1.0f + exp2_(-L2E * damping[0]));
  const int   nsteps = stepsPtr[0];
  const float b2v    = b2[0];

  // window init: win[t*16+b] = x[(b0g+b)*24 + t]
  for (int e = tid; e < 384; e += NTHR) {
    int b = e & 15, t = e >> 4;
    win[t * 16 + b] = x[(b0g + b) * 24 + t];
  }
  __syncthreads();

  const int offA = cc * SRB + hi * 16;
  const int offS = (wave * 16 + cc) * 2;
  float prevp = 0.0f;
  float c1[4] = {0, 0, 0, 0}, c2s[4] = {0, 0, 0, 0};

  // ---- prologue: L0(0) of step 0 (h1(-1)=0, MFMA-free) -> h1s[0] ----
  {
    float4 xw = *(const float4*)&win[0 * 16 + hi * 4];
    float xa[4] = {xw.x, xw.y, xw.z, xw.w};
    #pragma unroll
    for (int r = 0; r < 4; ++r) {
      float hv = gatestep(fmaf(xa[r], wih0v[0], bias0v[0]),
                          fmaf(xa[r], wih0v[1], bias0v[1]),
                          fmaf(xa[r], wih0v[2], bias0v[2]),
                          fmaf(xa[r], wih0v[3], bias0v[3]), c1[r]);
      *(_Float16*)(h1s[0] + (hi * 4 + r) * SRB + offS) = (_Float16)hv;
    }
  }
  __syncthreads();
  uint4 a1lo = *(const uint4*)(h1s[0] + offA);
  uint4 a1hi = *(const uint4*)(h1s[0] + offA + 64);
  uint4 a2lo = make_uint4(0, 0, 0, 0), a2hi = make_uint4(0, 0, 0, 0);
  uint4 hflo = make_uint4(0, 0, 0, 0), hfhi = make_uint4(0, 0, 0, 0);

  // standard iteration core: MFMA L1(t) + L0(t+1), gatesteps, stores
#define CORE(PH, PB)                                                           \
  do {                                                                         \
    f32x4 acc1[4], acc0[4];                                                    \
    _Pragma("unroll")                                                          \
    for (int gt = 0; gt < 4; ++gt) {                                           \
      f32x4 tv = mfma16(a1lo, wB1[gt][0], bi1[gt]);                            \
      tv = mfma16(a1hi, wB1[gt][1], tv);                                       \
      tv = mfma16(a2lo, wB2[gt][0], tv);                                       \
      acc1[gt] = mfma16(a2hi, wB2[gt][1], tv);                                 \
    }                                                                          \
    float4 xw = *(const float4*)&win[(PH) * 16 + hi * 4];                      \
    float xa[4] = {xw.x, xw.y, xw.z, xw.w};                                    \
    _Pragma("unroll")                                                          \
    for (int gt = 0; gt < 4; ++gt) {                                           \
      f32x4 ai;                                                                \
      _Pragma("unroll")                                                        \
      for (int r = 0; r < 4; ++r) ai[r] = fmaf(xa[r], wih0v[gt], bias0v[gt]);  \
      f32x4 tv = mfma16(a1lo, wB0[gt][0], ai);                                 \
      acc0[gt] = mfma16(a1hi, wB0[gt][1], tv);                                 \
    }                                                                          \
    _Pragma("unroll")                                                          \
    for (int r = 0; r < 4; ++r) {                                              \
      float hv = gatestep(acc1[0][r], acc1[1][r], acc1[2][r], acc1[3][r],      \
                          c2s[r]);                                             \
      *(_Float16*)(h2s[PB] + (hi * 4 + r) * SRB + offS) = (_Float16)hv;        \
    }                                                                          \
    _Pragma("unroll")                                                          \
    for (int r = 0; r < 4; ++r) {                                              \
      float hv = gatestep(acc0[0][r], acc0[1][r], acc0[2][r], acc0[3][r],      \
                          c1[r]);                                              \
      *(_Float16*)(h1s[PB] + (hi * 4 + r) * SRB + offS) = (_Float16)hv;        \
    }                                                                          \
  } while (0)

#define LOADFRAGS(PB)                                                          \
  do {                                                                         \
    a1lo = *(const uint4*)(h1s[PB] + offA);                                    \
    a1hi = *(const uint4*)(h1s[PB] + offA + 64);                               \
    a2lo = *(const uint4*)(h2s[PB] + offA);                                    \
    a2hi = *(const uint4*)(h2s[PB] + offA + 64);                               \
  } while (0)

  for (int s = 0; s < nsteps; ++s) {
    // ---- t = 0: core + folded MLP(s-1) ----
    {
      int ph = s + 1; if (ph >= 24) ph -= 24;
      CORE(ph, 1);
      if (s > 0 && wave < 2) {
        uint4 m0 = wfm[(wave & 1) * 2 + 0][lane];
        uint4 m1 = wfm[(wave & 1) * 2 + 1][lane];
        f32x4 am;
        #pragma unroll
        for (int r = 0; r < 4; ++r) am[r] = b1vv;
        am = mfma16(hflo, m0, am);
        am = mfma16(hfhi, m1, am);
        float yp[4];
        #pragma unroll
        for (int r = 0; r < 4; ++r) yp[r] = fmaxf(am[r], 0.0f) * w2v;
        #pragma unroll
        for (int mask = 1; mask <= 8; mask <<= 1) {
          #pragma unroll
          for (int r = 0; r < 4; ++r) yp[r] += __shfl_xor(yp[r], mask);
        }
        if (cc == 0) {
          #pragma unroll
          for (int r = 0; r < 4; ++r) pm[wave][hi * 4 + r] = yp[r];
        }
      }
      __syncthreads();
      LOADFRAGS(1);
    }
    // ---- t = 1: core + folded blend/write of pred(s-1) ----
    {
      if (s > 0 && wave == 0 && lane < 16) {
        float y = pm[0][lane] + pm[1][lane] + b2v;
        float pd = (s == 1) ? y : fmaf(y, 1.0f - alpha, prevp * (alpha * 0.5f));
        prevp = pd;
        int slot = (s - 1) % 24;
        win[slot * 16 + lane] = pd;
        out[(long)(b0g + lane) * nsteps + (s - 1)] = pd;
      }
      int ph = s + 2; if (ph >= 24) ph -= 24;
      CORE(ph, 0);
      __syncthreads();
      LOADFRAGS(0);
    }
    // ---- t = 2..22 ----
    for (int t = 2; t < 23; ++t) {
      int pb = (t + 1) & 1;
      int ph = s + t + 1; if (ph >= 24) ph -= 24;
      CORE(ph, pb);
      __syncthreads();
      LOADFRAGS(pb);
    }
    // ---- t = 23: L1(23) + L0(0) of next step; reset chains ----
    {
      f32x4 acc1[4];
      #pragma unroll
      for (int gt = 0; gt < 4; ++gt) {
        f32x4 tv = mfma16(a1lo, wB1[gt][0], bi1[gt]);
        tv = mfma16(a1hi, wB1[gt][1], tv);
        tv = mfma16(a2lo, wB2[gt][0], tv);
        acc1[gt] = mfma16(a2hi, wB2[gt][1], tv);
      }
      #pragma unroll
      for (int r = 0; r < 4; ++r) {
        float hv = gatestep(acc1[0][r], acc1[1][r], acc1[2][r], acc1[3][r],
                            c2s[r]);
        *(_Float16*)(h2s[0] + (hi * 4 + r) * SRB + offS) = (_Float16)hv;
      }
      if (s < nsteps - 1) {
        int ph = s + 1; if (ph >= 24) ph -= 24;   // stream[s+1]
        float4 xw = *(const float4*)&win[ph * 16 + hi * 4];
        float xa[4] = {xw.x, xw.y, xw.z, xw.w};
        #pragma unroll
        for (int r = 0; r < 4; ++r) {
          c1[r] = 0.0f;
          float hv = gatestep(fmaf(xa[r], wih0v[0], bias0v[0]),
                              fmaf(xa[r], wih0v[1], bias0v[1]),
                              fmaf(xa[r], wih0v[2], bias0v[2]),
                              fmaf(xa[r], wih0v[3], bias0v[3]), c1[r]);
          *(_Float16*)(h1s[0] + (hi * 4 + r) * SRB + offS) = (_Float16)hv;
        }
      }
      #pragma unroll
      for (int r = 0; r < 4; ++r) c2s[r] = 0.0f;
      __syncthreads();
      a1lo = *(const uint4*)(h1s[0] + offA);
      a1hi = *(const uint4*)(h1s[0] + offA + 64);
      a2lo = make_uint4(0, 0, 0, 0);
      a2hi = make_uint4(0, 0, 0, 0);
      hflo = *(const uint4*)(h2s[0] + offA);
      hfhi = *(const uint4*)(h2s[0] + offA + 64);
    }
  } // s

  // ---- tail: MLP + blend for the final step ----
  if (wave < 2) {
    uint4 m0 = wfm[(wave & 1) * 2 + 0][lane];
    uint4 m1 = wfm[(wave & 1) * 2 + 1][lane];
    f32x4 am;
    #pragma unroll
    for (int r = 0; r < 4; ++r) am[r] = b1vv;
    am = mfma16(hflo, m0, am);
    am = mfma16(hfhi, m1, am);
    float yp[4];
    #pragma unroll
    for (int r = 0; r < 4; ++r) yp[r] = fmaxf(am[r], 0.0f) * w2v;
    #pragma unroll
    for (int mask = 1; mask <= 8; mask <<= 1) {
      #pragma unroll
      for (int r = 0; r < 4; ++r) yp[r] += __shfl_xor(yp[r], mask);
    }
    if (cc == 0) {
      #pragma unroll
      for (int r = 0; r < 4; ++r) pm[wave][hi * 4 + r] = yp[r];
    }
  }
  __syncthreads();
  if (wave == 0 && lane < 16) {
    float y = pm[0][lane] + pm[1][lane] + b2v;
    float pd = (nsteps == 1) ? y : fmaf(y, 1.0f - alpha, prevp * (alpha * 0.5f));
    out[(long)(b0g + lane) * nsteps + (nsteps - 1)] = pd;
  }
#undef CORE
#undef LOADFRAGS
}

extern "C" void kernel_launch(void* const* d_in, const int* in_sizes, int n_in,
                              void* d_out, int out_size, void* d_ws, size_t ws_size,
                              hipStream_t stream) {
  (void)in_sizes; (void)n_in; (void)out_size; (void)d_ws; (void)ws_size;
  lstm_forecast<<<NBLK, NTHR, 0, stream>>>(
      (const float*)d_in[0],
      (const float*)d_in[1],  (const float*)d_in[2],
      (const float*)d_in[3],  (const float*)d_in[4],
      (const float*)d_in[5],  (const float*)d_in[6],
      (const float*)d_in[7],  (const float*)d_in[8],
      (const float*)d_in[9],  (const float*)d_in[10],
      (const float*)d_in[11], (const float*)d_in[12],
      (const float*)d_in[13], (const int*)d_in[14],
      (float*)d_out);
}